// Round 1
// baseline (518.477 us; speedup 1.0000x reference)
//
#include <hip/hip_runtime.h>

#define NROWS 2048   // n
#define NOUT  4096   // out_feat
#define NIN   4096   // in_feat

#define BM 128
#define BN 128
#define BK 32

typedef __attribute__((ext_vector_type(8))) short bf16x8;
typedef __attribute__((ext_vector_type(4))) float f32x4;

// round-to-nearest-even f32 -> bf16 bits
__device__ __forceinline__ unsigned short f2bf(float f) {
    unsigned int u = __float_as_uint(f);
    u += 0x7fff + ((u >> 16) & 1);
    return (unsigned short)(u >> 16);
}

// --- prep W: softmax over D=3 logits -> mean/var moments, stored bf16 ------
__global__ __launch_bounds__(256) void prep_w_kernel(
        const float* __restrict__ Wl,
        unsigned short* __restrict__ wmean,
        unsigned short* __restrict__ wvar) {
    const long long total = (long long)NOUT * NIN;   // 16,777,216
    const long long idx = ((long long)blockIdx.x * 256 + threadIdx.x) * 4;
    float4 l0 = *(const float4*)(Wl + idx);
    float4 l1 = *(const float4*)(Wl + total + idx);
    float4 l2 = *(const float4*)(Wl + 2 * total + idx);
    float a0[4] = {l0.x, l0.y, l0.z, l0.w};
    float a1[4] = {l1.x, l1.y, l1.z, l1.w};
    float a2[4] = {l2.x, l2.y, l2.z, l2.w};
    unsigned short mo[4], vo[4];
#pragma unroll
    for (int j = 0; j < 4; ++j) {
        float e0 = __expf(a0[j]);
        float e1 = __expf(a1[j]);
        float e2 = __expf(a2[j]);
        float inv = 1.0f / (e0 + e1 + e2);
        float mean = (e2 - e0) * inv;   // values {-1,0,1}
        float sq   = (e2 + e0) * inv;   // values^2 {1,0,1}
        float var  = fmaf(-mean, mean, sq);
        mo[j] = f2bf(mean);
        vo[j] = f2bf(var);
    }
    *(ushort4*)(wmean + idx) = make_ushort4(mo[0], mo[1], mo[2], mo[3]);
    *(ushort4*)(wvar  + idx) = make_ushort4(vo[0], vo[1], vo[2], vo[3]);
}

// --- prep x: f32 -> bf16 x and bf16 x^2 ------------------------------------
__global__ __launch_bounds__(256) void prep_x_kernel(
        const float* __restrict__ x,
        unsigned short* __restrict__ xbf,
        unsigned short* __restrict__ x2bf) {
    const long long idx = ((long long)blockIdx.x * 256 + threadIdx.x) * 4;
    float4 v = *(const float4*)(x + idx);
    float a[4] = {v.x, v.y, v.z, v.w};
    unsigned short xo[4], x2o[4];
#pragma unroll
    for (int j = 0; j < 4; ++j) {
        xo[j]  = f2bf(a[j]);
        x2o[j] = f2bf(a[j] * a[j]);
    }
    *(ushort4*)(xbf + idx)  = make_ushort4(xo[0], xo[1], xo[2], xo[3]);
    *(ushort4*)(x2bf + idx) = make_ushort4(x2o[0], x2o[1], x2o[2], x2o[3]);
}

// --- GEMM: C[m,o] = sum_k A[m,k]*W[o,k], both bf16 K-contiguous ------------
// grid.z = 0 -> (xbf, wmean) + bias_mean ; grid.z = 1 -> (x2bf, wvar) + bias_var
__global__ __launch_bounds__(256) void gemm_moments_kernel(
        const unsigned short* __restrict__ xbf,
        const unsigned short* __restrict__ x2bf,
        const unsigned short* __restrict__ wmean,
        const unsigned short* __restrict__ wvar,
        const float* __restrict__ blogits,
        float* __restrict__ out) {
    __shared__ __align__(16) unsigned short sA[BM * BK];   // 8 KB
    __shared__ __align__(16) unsigned short sB[BN * BK];   // 8 KB

    const int z = blockIdx.z;
    const unsigned short* __restrict__ A = z ? x2bf : xbf;     // (NROWS, NIN)
    const unsigned short* __restrict__ W = z ? wvar : wmean;   // (NOUT, NIN)

    const int m0 = blockIdx.y * BM;
    const int o0 = blockIdx.x * BN;
    const int tid  = threadIdx.x;
    const int lane = tid & 63;
    const int wave = tid >> 6;   // 0..3
    const int wm = wave >> 1;    // row half of the 128x128 tile
    const int wn = wave & 1;     // col half

    // staging: each global_load_lds moves 64 lanes x 16B = 16 rows x 32 bf16
    const int r_in = lane >> 2;        // 0..15 row within 16-row chunk
    const int c8   = (lane & 3) * 8;   // k-offset in elements: 0,8,16,24
    const int q0 = wave * 2;

    f32x4 acc[4][4];
#pragma unroll
    for (int i = 0; i < 4; ++i)
#pragma unroll
        for (int j = 0; j < 4; ++j) acc[i][j] = (f32x4){0.f, 0.f, 0.f, 0.f};

    for (int k0 = 0; k0 < NIN; k0 += BK) {
#pragma unroll
        for (int t = 0; t < 2; ++t) {
            const int q = q0 + t;   // 0..7: 16-row chunk index
            const unsigned short* ga = A + (long long)(m0 + q * 16 + r_in) * NIN + k0 + c8;
            __builtin_amdgcn_global_load_lds(
                (const __attribute__((address_space(1))) void*)ga,
                (__attribute__((address_space(3))) void*)(sA + q * (16 * BK)),
                16, 0, 0);
            const unsigned short* gb = W + (long long)(o0 + q * 16 + r_in) * NIN + k0 + c8;
            __builtin_amdgcn_global_load_lds(
                (const __attribute__((address_space(1))) void*)gb,
                (__attribute__((address_space(3))) void*)(sB + q * (16 * BK)),
                16, 0, 0);
        }
        __syncthreads();   // drains vmcnt: tiles resident in LDS

        const int quad = lane >> 4;   // 0..3 -> k-subrange
        const int mr   = lane & 15;   // row/col within 16
        bf16x8 afrag[4], bfrag[4];
#pragma unroll
        for (int t = 0; t < 4; ++t) {
            afrag[t] = *(const bf16x8*)(sA + (wm * 64 + t * 16 + mr) * BK + quad * 8);
            bfrag[t] = *(const bf16x8*)(sB + (wn * 64 + t * 16 + mr) * BK + quad * 8);
        }
#pragma unroll
        for (int tm = 0; tm < 4; ++tm)
#pragma unroll
            for (int tn = 0; tn < 4; ++tn)
                acc[tm][tn] = __builtin_amdgcn_mfma_f32_16x16x32_bf16(
                    afrag[tm], bfrag[tn], acc[tm][tn], 0, 0, 0);
        __syncthreads();   // before next overwrite of LDS
    }

    // epilogue: C/D layout col = lane&15 (o), row = (lane>>4)*4 + reg (m)
    const int quad = lane >> 4;
    const int cn   = lane & 15;
#pragma unroll
    for (int tn = 0; tn < 4; ++tn) {
        const int o = o0 + wn * 64 + tn * 16 + cn;
        float l0 = blogits[o];
        float l1 = blogits[NOUT + o];
        float l2 = blogits[2 * NOUT + o];
        float e0 = __expf(l0), e1 = __expf(l1), e2 = __expf(l2);
        float inv = 1.0f / (e0 + e1 + e2);
        float bm = (e2 - e0) * inv;
        float bias = z ? fmaf(-bm, bm, (e2 + e0) * inv) : bm;
#pragma unroll
        for (int tm = 0; tm < 4; ++tm) {
            const int mb = m0 + wm * 64 + tm * 16 + quad * 4;
            float* op = out + (long long)mb * (2 * NOUT) + (long long)z * NOUT + o;
#pragma unroll
            for (int r = 0; r < 4; ++r) {
                op[(long long)r * (2 * NOUT)] = acc[tm][tn][r] + bias;
            }
        }
    }
}

extern "C" void kernel_launch(void* const* d_in, const int* in_sizes, int n_in,
                              void* d_out, int out_size, void* d_ws, size_t ws_size,
                              hipStream_t stream) {
    const float* x  = (const float*)d_in[0];   // (2048, 4096)
    const float* Wl = (const float*)d_in[1];   // (3, 4096, 4096)
    const float* bl = (const float*)d_in[2];   // (3, 4096)
    float* out = (float*)d_out;                // (2048, 2, 4096)

    // workspace layout (bytes): wmean 32M | wvar 32M | xbf 16M | x2bf 16M = 100.7 MB
    char* ws = (char*)d_ws;
    unsigned short* wmean = (unsigned short*)(ws);
    unsigned short* wvar  = (unsigned short*)(ws + 33554432);
    unsigned short* xbf   = (unsigned short*)(ws + 67108864);
    unsigned short* x2bf  = (unsigned short*)(ws + 83886080);

    prep_w_kernel<<<16384, 256, 0, stream>>>(Wl, wmean, wvar);   // 16.7M elems / 4 / 256
    prep_x_kernel<<<8192, 256, 0, stream>>>(x, xbf, x2bf);       // 8.4M elems / 4 / 256

    dim3 grid(NOUT / BN, NROWS / BM, 2);                         // 32 x 16 x 2
    gemm_moments_kernel<<<grid, 256, 0, stream>>>(xbf, x2bf, wmean, wvar, bl, out);
}

// Round 2
// 514.850 us; speedup vs baseline: 1.0070x; 1.0070x over previous
//
#include <hip/hip_runtime.h>

#define NROWS 2048   // n
#define NOUT  4096   // out_feat
#define NIN   4096   // in_feat

#define BM 128
#define BN 128
#define BK 32

typedef __attribute__((ext_vector_type(8))) short bf16x8;
typedef __attribute__((ext_vector_type(4))) float f32x4;

// round-to-nearest-even f32 -> bf16 bits
__device__ __forceinline__ unsigned short f2bf(float f) {
    unsigned int u = __float_as_uint(f);
    u += 0x7fff + ((u >> 16) & 1);
    return (unsigned short)(u >> 16);
}

// --- prep W: softmax over D=3 logits -> mean/var moments, stored bf16 ------
__global__ __launch_bounds__(256) void prep_w_kernel(
        const float* __restrict__ Wl,
        unsigned short* __restrict__ wmean,
        unsigned short* __restrict__ wvar) {
    const long long total = (long long)NOUT * NIN;   // 16,777,216
    const long long idx = ((long long)blockIdx.x * 256 + threadIdx.x) * 4;
    float4 l0 = *(const float4*)(Wl + idx);
    float4 l1 = *(const float4*)(Wl + total + idx);
    float4 l2 = *(const float4*)(Wl + 2 * total + idx);
    float a0[4] = {l0.x, l0.y, l0.z, l0.w};
    float a1[4] = {l1.x, l1.y, l1.z, l1.w};
    float a2[4] = {l2.x, l2.y, l2.z, l2.w};
    unsigned short mo[4], vo[4];
#pragma unroll
    for (int j = 0; j < 4; ++j) {
        float e0 = __expf(a0[j]);
        float e1 = __expf(a1[j]);
        float e2 = __expf(a2[j]);
        float inv = 1.0f / (e0 + e1 + e2);
        float mean = (e2 - e0) * inv;   // values {-1,0,1}
        float sq   = (e2 + e0) * inv;   // values^2 {1,0,1}
        float var  = fmaf(-mean, mean, sq);
        mo[j] = f2bf(mean);
        vo[j] = f2bf(var);
    }
    *(ushort4*)(wmean + idx) = make_ushort4(mo[0], mo[1], mo[2], mo[3]);
    *(ushort4*)(wvar  + idx) = make_ushort4(vo[0], vo[1], vo[2], vo[3]);
}

// --- prep x: f32 -> bf16 x and bf16 x^2 ------------------------------------
__global__ __launch_bounds__(256) void prep_x_kernel(
        const float* __restrict__ x,
        unsigned short* __restrict__ xbf,
        unsigned short* __restrict__ x2bf) {
    const long long idx = ((long long)blockIdx.x * 256 + threadIdx.x) * 4;
    float4 v = *(const float4*)(x + idx);
    float a[4] = {v.x, v.y, v.z, v.w};
    unsigned short xo[4], x2o[4];
#pragma unroll
    for (int j = 0; j < 4; ++j) {
        xo[j]  = f2bf(a[j]);
        x2o[j] = f2bf(a[j] * a[j]);
    }
    *(ushort4*)(xbf + idx)  = make_ushort4(xo[0], xo[1], xo[2], xo[3]);
    *(ushort4*)(x2bf + idx) = make_ushort4(x2o[0], x2o[1], x2o[2], x2o[3]);
}

// --- GEMM: C[m,o] = sum_k A[m,k]*W[o,k], both bf16 K-contiguous ------------
// LDS layout is k-chunk swizzled: 16B chunk c of row R lives at slot
// s = (c + (R>>1)) & 3  -> fragment reads spread over all 8 four-bank groups
// (2 lanes/group = free 2-way) instead of 2 groups (8-way conflict).
// grid.z = 0 -> (xbf, wmean) + bias_mean ; grid.z = 1 -> (x2bf, wvar) + bias_var
__global__ __launch_bounds__(256) void gemm_moments_kernel(
        const unsigned short* __restrict__ xbf,
        const unsigned short* __restrict__ x2bf,
        const unsigned short* __restrict__ wmean,
        const unsigned short* __restrict__ wvar,
        const float* __restrict__ blogits,
        float* __restrict__ out) {
    __shared__ __align__(16) unsigned short sA[BM * BK];   // 8 KB
    __shared__ __align__(16) unsigned short sB[BN * BK];   // 8 KB

    const int z = blockIdx.z;
    const unsigned short* __restrict__ A = z ? x2bf : xbf;     // (NROWS, NIN)
    const unsigned short* __restrict__ W = z ? wvar : wmean;   // (NOUT, NIN)

    const int m0 = blockIdx.y * BM;
    const int o0 = blockIdx.x * BN;
    const int tid  = threadIdx.x;
    const int lane = tid & 63;
    const int wave = tid >> 6;   // 0..3
    const int wm = wave >> 1;    // row half of the 128x128 tile
    const int wn = wave & 1;     // col half

    // staging: each global_load_lds moves 64 lanes x 16B = 16 rows x 32 bf16.
    // Lane L lands at LDS slot (row r = L>>2, slot s = L&3); to realize the
    // swizzle it must FETCH global chunk c_g = (s - (r>>1)) & 3.
    const int r_in = lane >> 2;                         // 0..15
    const int c_g  = (((lane & 3) - (r_in >> 1)) & 3);  // swizzled global chunk
    const int c8   = c_g * 8;                           // k-offset (elements)
    const int q0 = wave * 2;

    // loop-carried global staging pointers (avoid per-iter 64-bit addr calc)
    const unsigned short* pA[2];
    const unsigned short* pB[2];
#pragma unroll
    for (int t = 0; t < 2; ++t) {
        const int q = q0 + t;
        pA[t] = A + (long long)(m0 + q * 16 + r_in) * NIN + c8;
        pB[t] = W + (long long)(o0 + q * 16 + r_in) * NIN + c8;
    }

    f32x4 acc[4][4];
#pragma unroll
    for (int i = 0; i < 4; ++i)
#pragma unroll
        for (int j = 0; j < 4; ++j) acc[i][j] = (f32x4){0.f, 0.f, 0.f, 0.f};

    const int quad = lane >> 4;   // 0..3 -> k-subrange (logical chunk)
    const int mr   = lane & 15;   // row within 16
    // swizzled LDS slot for fragment reads (same for A and B, all t):
    const int slot = (quad + (mr >> 1)) & 3;

    for (int k0 = 0; k0 < NIN; k0 += BK) {
#pragma unroll
        for (int t = 0; t < 2; ++t) {
            const int q = q0 + t;
            __builtin_amdgcn_global_load_lds(
                (const __attribute__((address_space(1))) void*)pA[t],
                (__attribute__((address_space(3))) void*)(sA + q * (16 * BK)),
                16, 0, 0);
            __builtin_amdgcn_global_load_lds(
                (const __attribute__((address_space(1))) void*)pB[t],
                (__attribute__((address_space(3))) void*)(sB + q * (16 * BK)),
                16, 0, 0);
            pA[t] += BK;
            pB[t] += BK;
        }
        __syncthreads();   // drains vmcnt: tiles resident in LDS

        bf16x8 afrag[4], bfrag[4];
#pragma unroll
        for (int t = 0; t < 4; ++t) {
            const int ra = wm * 64 + t * 16 + mr;
            const int rb = wn * 64 + t * 16 + mr;
            afrag[t] = *(const bf16x8*)(sA + ra * BK + slot * 8);
            bfrag[t] = *(const bf16x8*)(sB + rb * BK + slot * 8);
        }
#pragma unroll
        for (int tm = 0; tm < 4; ++tm)
#pragma unroll
            for (int tn = 0; tn < 4; ++tn)
                acc[tm][tn] = __builtin_amdgcn_mfma_f32_16x16x32_bf16(
                    afrag[tm], bfrag[tn], acc[tm][tn], 0, 0, 0);
        __syncthreads();   // before next overwrite of LDS
    }

    // epilogue: C/D layout col = lane&15 (o), row = (lane>>4)*4 + reg (m)
    const int cn = lane & 15;
#pragma unroll
    for (int tn = 0; tn < 4; ++tn) {
        const int o = o0 + wn * 64 + tn * 16 + cn;
        float l0 = blogits[o];
        float l1 = blogits[NOUT + o];
        float l2 = blogits[2 * NOUT + o];
        float e0 = __expf(l0), e1 = __expf(l1), e2 = __expf(l2);
        float inv = 1.0f / (e0 + e1 + e2);
        float bm = (e2 - e0) * inv;
        float bias = z ? fmaf(-bm, bm, (e2 + e0) * inv) : bm;
#pragma unroll
        for (int tm = 0; tm < 4; ++tm) {
            const int mb = m0 + wm * 64 + tm * 16 + quad * 4;
            float* op = out + (long long)mb * (2 * NOUT) + (long long)z * NOUT + o;
#pragma unroll
            for (int r = 0; r < 4; ++r) {
                op[(long long)r * (2 * NOUT)] = acc[tm][tn][r] + bias;
            }
        }
    }
}

extern "C" void kernel_launch(void* const* d_in, const int* in_sizes, int n_in,
                              void* d_out, int out_size, void* d_ws, size_t ws_size,
                              hipStream_t stream) {
    const float* x  = (const float*)d_in[0];   // (2048, 4096)
    const float* Wl = (const float*)d_in[1];   // (3, 4096, 4096)
    const float* bl = (const float*)d_in[2];   // (3, 4096)
    float* out = (float*)d_out;                // (2048, 2, 4096)

    // workspace layout (bytes): wmean 32M | wvar 32M | xbf 16M | x2bf 16M = 100.7 MB
    char* ws = (char*)d_ws;
    unsigned short* wmean = (unsigned short*)(ws);
    unsigned short* wvar  = (unsigned short*)(ws + 33554432);
    unsigned short* xbf   = (unsigned short*)(ws + 67108864);
    unsigned short* x2bf  = (unsigned short*)(ws + 83886080);

    prep_w_kernel<<<16384, 256, 0, stream>>>(Wl, wmean, wvar);   // 16.7M elems / 4 / 256
    prep_x_kernel<<<8192, 256, 0, stream>>>(x, xbf, x2bf);       // 8.4M elems / 4 / 256

    dim3 grid(NOUT / BN, NROWS / BM, 2);                         // 32 x 16 x 2
    gemm_moments_kernel<<<grid, 256, 0, stream>>>(xbf, x2bf, wmean, wvar, bl, out);
}

// Round 3
// 491.092 us; speedup vs baseline: 1.0558x; 1.0484x over previous
//
#include <hip/hip_runtime.h>

#define NROWS 2048   // n
#define NOUT  4096   // out_feat
#define NIN   4096   // in_feat

#define BM 128
#define BN 128
#define BK 64

typedef __attribute__((ext_vector_type(8))) short bf16x8;
typedef __attribute__((ext_vector_type(4))) float f32x4;

// round-to-nearest-even f32 -> bf16 bits
__device__ __forceinline__ unsigned short f2bf(float f) {
    unsigned int u = __float_as_uint(f);
    u += 0x7fff + ((u >> 16) & 1);
    return (unsigned short)(u >> 16);
}

// --- prep W: softmax over D=3 logits -> mean/var moments, stored bf16 ------
__global__ __launch_bounds__(256) void prep_w_kernel(
        const float* __restrict__ Wl,
        unsigned short* __restrict__ wmean,
        unsigned short* __restrict__ wvar) {
    const long long total = (long long)NOUT * NIN;   // 16,777,216
    const long long idx = ((long long)blockIdx.x * 256 + threadIdx.x) * 4;
    float4 l0 = *(const float4*)(Wl + idx);
    float4 l1 = *(const float4*)(Wl + total + idx);
    float4 l2 = *(const float4*)(Wl + 2 * total + idx);
    float a0[4] = {l0.x, l0.y, l0.z, l0.w};
    float a1[4] = {l1.x, l1.y, l1.z, l1.w};
    float a2[4] = {l2.x, l2.y, l2.z, l2.w};
    unsigned short mo[4], vo[4];
#pragma unroll
    for (int j = 0; j < 4; ++j) {
        float e0 = __expf(a0[j]);
        float e1 = __expf(a1[j]);
        float e2 = __expf(a2[j]);
        float inv = 1.0f / (e0 + e1 + e2);
        float mean = (e2 - e0) * inv;   // values {-1,0,1}
        float sq   = (e2 + e0) * inv;   // values^2 {1,0,1}
        float var  = fmaf(-mean, mean, sq);
        mo[j] = f2bf(mean);
        vo[j] = f2bf(var);
    }
    *(ushort4*)(wmean + idx) = make_ushort4(mo[0], mo[1], mo[2], mo[3]);
    *(ushort4*)(wvar  + idx) = make_ushort4(vo[0], vo[1], vo[2], vo[3]);
}

// --- prep x: f32 -> bf16 x and bf16 x^2 ------------------------------------
__global__ __launch_bounds__(256) void prep_x_kernel(
        const float* __restrict__ x,
        unsigned short* __restrict__ xbf,
        unsigned short* __restrict__ x2bf) {
    const long long idx = ((long long)blockIdx.x * 256 + threadIdx.x) * 4;
    float4 v = *(const float4*)(x + idx);
    float a[4] = {v.x, v.y, v.z, v.w};
    unsigned short xo[4], x2o[4];
#pragma unroll
    for (int j = 0; j < 4; ++j) {
        xo[j]  = f2bf(a[j]);
        x2o[j] = f2bf(a[j] * a[j]);
    }
    *(ushort4*)(xbf + idx)  = make_ushort4(xo[0], xo[1], xo[2], xo[3]);
    *(ushort4*)(x2bf + idx) = make_ushort4(x2o[0], x2o[1], x2o[2], x2o[3]);
}

// --- GEMM: C[m,o] = sum_k A[m,k]*W[o,k], both bf16 K-contiguous ------------
// BK=64: 64 k-iters (half the barrier drains of BK=32), 32 MFMA/wave/iter.
// LDS swizzle: rows are 8 x 16B granules; granule g of row r lives at slot
// g ^ (r & 7). Fragment reads then spread each 16-lane quad over all 8
// four-bank groups (2 lanes each = free). Staging lanes fetch the inverse-
// permuted global granule (same 128 B row -> coalescing preserved).
// grid.z = 0 -> (xbf, wmean) + bias_mean ; z = 1 -> (x2bf, wvar) + bias_var
__global__ __launch_bounds__(256, 3) void gemm_moments_kernel(
        const unsigned short* __restrict__ xbf,
        const unsigned short* __restrict__ x2bf,
        const unsigned short* __restrict__ wmean,
        const unsigned short* __restrict__ wvar,
        const float* __restrict__ blogits,
        float* __restrict__ out) {
    __shared__ __align__(16) unsigned short sA[BM * BK];   // 16 KB
    __shared__ __align__(16) unsigned short sB[BN * BK];   // 16 KB

    const int z = blockIdx.z;
    const unsigned short* __restrict__ A = z ? x2bf : xbf;     // (NROWS, NIN)
    const unsigned short* __restrict__ W = z ? wvar : wmean;   // (NOUT, NIN)

    const int m0 = blockIdx.y * BM;
    const int o0 = blockIdx.x * BN;
    const int tid  = threadIdx.x;
    const int lane = tid & 63;
    const int wave = tid >> 6;   // 0..3
    const int wm = wave >> 1;    // row half of the 128x128 tile
    const int wn = wave & 1;     // col half

    // staging: each global_load_lds moves 64 lanes x 16B = 8 rows x 64 bf16.
    // Lane L lands at LDS (row r = L>>3, slot s = L&7); row&7 == r, so the
    // lane must FETCH global granule g = s ^ r to realize the swizzle.
    const int r_in = lane >> 3;                  // 0..7 row within 8-row chunk
    const int g_f  = (lane & 7) ^ r_in;          // swizzled global granule
    const int c8   = g_f * 8;                    // k-offset (elements)

    // 16 chunks of 8 rows per tile; wave handles chunks wave*4 .. wave*4+3
    const unsigned short* pA[4];
    const unsigned short* pB[4];
#pragma unroll
    for (int t = 0; t < 4; ++t) {
        const int q = wave * 4 + t;
        pA[t] = A + (long long)(m0 + q * 8 + r_in) * NIN + c8;
        pB[t] = W + (long long)(o0 + q * 8 + r_in) * NIN + c8;
    }

    f32x4 acc[4][4];
#pragma unroll
    for (int i = 0; i < 4; ++i)
#pragma unroll
        for (int j = 0; j < 4; ++j) acc[i][j] = (f32x4){0.f, 0.f, 0.f, 0.f};

    const int quad = lane >> 4;   // 0..3 -> 16B granule within 32-elem k-step
    const int mr   = lane & 15;   // row within 16

    for (int k0 = 0; k0 < NIN; k0 += BK) {
#pragma unroll
        for (int t = 0; t < 4; ++t) {
            const int q = wave * 4 + t;
            __builtin_amdgcn_global_load_lds(
                (const __attribute__((address_space(1))) void*)pA[t],
                (__attribute__((address_space(3))) void*)(sA + q * (8 * BK)),
                16, 0, 0);
            __builtin_amdgcn_global_load_lds(
                (const __attribute__((address_space(1))) void*)pB[t],
                (__attribute__((address_space(3))) void*)(sB + q * (8 * BK)),
                16, 0, 0);
            pA[t] += BK;
            pB[t] += BK;
        }
        __syncthreads();   // drains vmcnt: tiles resident in LDS

#pragma unroll
        for (int ks = 0; ks < 2; ++ks) {
            bf16x8 afrag[4], bfrag[4];
#pragma unroll
            for (int t = 0; t < 4; ++t) {
                const int ra = wm * 64 + t * 16 + mr;
                const int rb = wn * 64 + t * 16 + mr;
                const int slot = (ks * 4 + quad) ^ (mr & 7);
                afrag[t] = *(const bf16x8*)(sA + ra * BK + slot * 8);
                bfrag[t] = *(const bf16x8*)(sB + rb * BK + slot * 8);
            }
#pragma unroll
            for (int tm = 0; tm < 4; ++tm)
#pragma unroll
                for (int tn = 0; tn < 4; ++tn)
                    acc[tm][tn] = __builtin_amdgcn_mfma_f32_16x16x32_bf16(
                        afrag[tm], bfrag[tn], acc[tm][tn], 0, 0, 0);
        }
        __syncthreads();   // before next overwrite of LDS
    }

    // epilogue: C/D layout col = lane&15 (o), row = (lane>>4)*4 + reg (m)
    const int cn = lane & 15;
#pragma unroll
    for (int tn = 0; tn < 4; ++tn) {
        const int o = o0 + wn * 64 + tn * 16 + cn;
        float l0 = blogits[o];
        float l1 = blogits[NOUT + o];
        float l2 = blogits[2 * NOUT + o];
        float e0 = __expf(l0), e1 = __expf(l1), e2 = __expf(l2);
        float inv = 1.0f / (e0 + e1 + e2);
        float bm = (e2 - e0) * inv;
        float bias = z ? fmaf(-bm, bm, (e2 + e0) * inv) : bm;
#pragma unroll
        for (int tm = 0; tm < 4; ++tm) {
            const int mb = m0 + wm * 64 + tm * 16 + quad * 4;
            float* op = out + (long long)mb * (2 * NOUT) + (long long)z * NOUT + o;
#pragma unroll
            for (int r = 0; r < 4; ++r) {
                op[(long long)r * (2 * NOUT)] = acc[tm][tn][r] + bias;
            }
        }
    }
}

extern "C" void kernel_launch(void* const* d_in, const int* in_sizes, int n_in,
                              void* d_out, int out_size, void* d_ws, size_t ws_size,
                              hipStream_t stream) {
    const float* x  = (const float*)d_in[0];   // (2048, 4096)
    const float* Wl = (const float*)d_in[1];   // (3, 4096, 4096)
    const float* bl = (const float*)d_in[2];   // (3, 4096)
    float* out = (float*)d_out;                // (2048, 2, 4096)

    // workspace layout (bytes): wmean 32M | wvar 32M | xbf 16M | x2bf 16M = 100.7 MB
    char* ws = (char*)d_ws;
    unsigned short* wmean = (unsigned short*)(ws);
    unsigned short* wvar  = (unsigned short*)(ws + 33554432);
    unsigned short* xbf   = (unsigned short*)(ws + 67108864);
    unsigned short* x2bf  = (unsigned short*)(ws + 83886080);

    prep_w_kernel<<<16384, 256, 0, stream>>>(Wl, wmean, wvar);   // 16.7M elems / 4 / 256
    prep_x_kernel<<<8192, 256, 0, stream>>>(x, xbf, x2bf);       // 8.4M elems / 4 / 256

    dim3 grid(NOUT / BN, NROWS / BM, 2);                         // 32 x 16 x 2
    gemm_moments_kernel<<<grid, 256, 0, stream>>>(xbf, x2bf, wmean, wvar, bl, out);
}